// Round 12
// baseline (939.382 us; speedup 1.0000x reference)
//
#include <hip/hip_runtime.h>
#include <cstdint>
#include <cstddef>

typedef float f32x4 __attribute__((ext_vector_type(4)));
typedef float f32x2 __attribute__((ext_vector_type(2)));
typedef short s16x8 __attribute__((ext_vector_type(8)));
typedef unsigned short u16;

static __device__ __forceinline__ u16 f2bf(float f) {
    uint32_t x = __float_as_uint(f);
    x += 0x7fffu + ((x >> 16) & 1u);   // round-to-nearest-even to bf16
    return (u16)(x >> 16);
}
static __device__ __forceinline__ float bf2f(u16 h) {
    return __uint_as_float(((uint32_t)h) << 16);
}
static __device__ __forceinline__ void split8(const float* fv, s16x8& hh, s16x8& ll) {
#pragma unroll
    for (int i = 0; i < 8; ++i) {
        u16 h = f2bf(fv[i]); hh[i] = (short)h; ll[i] = (short)f2bf(fv[i] - bf2f(h));
    }
}

// Raw barrier with ONLY an LDS drain (no vmcnt) — prefetch loads / hseq
// stores stay in flight across the per-step barriers.
static __device__ __forceinline__ void bar_lds() {
    asm volatile("s_waitcnt lgkmcnt(0)" ::: "memory");
    __builtin_amdgcn_s_barrier();
    asm volatile("" ::: "memory");
}

#define GLDS(SRC, DST) __builtin_amdgcn_global_load_lds( \
    (const __attribute__((address_space(1))) void*)(SRC), \
    (__attribute__((address_space(3))) void*)(DST), 16, 0, 0)

// ---------------- zero the pipeline flags (every launch; replay-safe) ------
__global__ void k_zero(int* __restrict__ p, int n) {
    int i = blockIdx.x * 256 + threadIdx.x;
    if (i < n) p[i] = 0;
}

// ---------------- split fp32 -> bf16 hi/lo ----------------
__global__ void k_split(const float* __restrict__ src, u16* __restrict__ hi,
                        u16* __restrict__ lo, int n) {
    int i = blockIdx.x * 256 + threadIdx.x;
    if (i < n) {
        float f = src[i];
        u16 h = f2bf(f);
        hi[i] = h;
        lo[i] = f2bf(f - bf2f(h));
    }
}

// =================== fused pipeline kernel ===================
// grid = 256 blocks x 512 threads, 1 block/CU (LDS-forced).
//   blocks   0..63 : L0 recurrence (1 batch), gated on gemmflag[b*4+quarter];
//                    publish h1flag per 16 steps
//   blocks  64..127: L1 recurrence (consume xgflag) + MLP head
//   blocks 128..255: workers: 2 panel-triples of G0 (quarter-major order,
//                    A-panel-local), inter-tile xg1 drains, then blocking xg1.
// G0 task: panel-triple (b, q): xg0 rows b*512+q*128..+128, all 3 nb tiles.

struct SmemRecur { float hsh[128]; float hp[8][384]; };
struct SmemG0    { u16 buf[2][4][4096]; };   // [buf][Ah,Al,Bh,Bl][128*32] 64KB
struct SmemX     { u16 ah[2048]; u16 al[2048]; int decision; };
struct SmemWorker { SmemG0 g0; SmemX x; };
union Smem {
    SmemRecur r;
    SmemWorker w;
    char force_one_block_per_cu[98304];   // 96KB: strictly 1 block/CU
};

// ---- one G0 tile: xg0 rows [b*512+q*128, +128) x cols [nb*128, +128) ----
__device__ void g0_tile(int b, int q, int nb,
        const float* __restrict__ x, const u16* __restrict__ w0h,
        const u16* __restrict__ w0l, const float* __restrict__ bih0,
        float* __restrict__ xg, SmemG0& g)
{
    const int tid = threadIdx.x, lane = tid & 63, wv = tid >> 6;
    const int wm = wv >> 2, wn = wv & 3;          // 2 x 4 wave grid
    const int rsel = lane & 15, koff = (lane >> 4) * 8;

    const int ar = tid >> 2, ak = (tid & 3) * 8;
    const float* aptr = x + ((size_t)(b * 512 + q * 128 + ar)) * 2048 + ak;
    const u16* bhp = w0h + (size_t)(nb * 128 + (tid >> 2)) * 2048 + ak;
    const u16* blp = w0l + (size_t)(nb * 128 + (tid >> 2)) * 2048 + ak;

    f32x4 acc[4][2];
    const f32x4 vz = {0.f, 0.f, 0.f, 0.f};
#pragma unroll
    for (int f = 0; f < 4; ++f) { acc[f][0] = vz; acc[f][1] = vz; }

    {   // prologue: stage ks=0 into buf 0
        GLDS(bhp, &g.buf[0][2][0] + tid * 8);
        GLDS(blp, &g.buf[0][3][0] + tid * 8);
        f32x4 a0 = *(const f32x4*)aptr, a1 = *(const f32x4*)(aptr + 4);
        float fv[8] = {a0[0],a0[1],a0[2],a0[3], a1[0],a1[1],a1[2],a1[3]};
        s16x8 hh, ll; split8(fv, hh, ll);
        *(s16x8*)&g.buf[0][0][ar * 32 + ak] = hh;
        *(s16x8*)&g.buf[0][1][ar * 32 + ak] = ll;
    }
    __syncthreads();

    for (int ks = 0; ks < 64; ++ks) {
        const int cur = ks & 1, nxt = cur ^ 1;
        const bool more = ks < 63;
        f32x4 a0, a1;
        if (more) {
            const int k0 = (ks + 1) * 32;
            GLDS(bhp + k0, &g.buf[nxt][2][0] + tid * 8);
            GLDS(blp + k0, &g.buf[nxt][3][0] + tid * 8);
            a0 = *(const f32x4*)(aptr + k0);
            a1 = *(const f32x4*)(aptr + k0 + 4);
        }
        {
            const u16* base = &g.buf[cur][0][0];
            s16x8 ah[4], al[4], bh2[2], bl2[2];
#pragma unroll
            for (int f = 0; f < 4; ++f) {
                const int row = wm * 64 + f * 16 + rsel;
                ah[f] = *(const s16x8*)&base[row * 32 + koff];
                al[f] = *(const s16x8*)&base[4096 + row * 32 + koff];
            }
#pragma unroll
            for (int j = 0; j < 2; ++j) {
                const int row = wn * 32 + j * 16 + rsel;
                bh2[j] = *(const s16x8*)&base[8192  + row * 32 + koff];
                bl2[j] = *(const s16x8*)&base[12288 + row * 32 + koff];
            }
#pragma unroll
            for (int j = 0; j < 2; ++j)
#pragma unroll
                for (int f = 0; f < 4; ++f) {
                    acc[f][j] = __builtin_amdgcn_mfma_f32_16x16x32_bf16(ah[f], bh2[j], acc[f][j], 0, 0, 0);
                    acc[f][j] = __builtin_amdgcn_mfma_f32_16x16x32_bf16(ah[f], bl2[j], acc[f][j], 0, 0, 0);
                    acc[f][j] = __builtin_amdgcn_mfma_f32_16x16x32_bf16(al[f], bh2[j], acc[f][j], 0, 0, 0);
                }
        }
        if (more) {
            float fv[8] = {a0[0],a0[1],a0[2],a0[3], a1[0],a1[1],a1[2],a1[3]};
            s16x8 hh, ll; split8(fv, hh, ll);
            *(s16x8*)&g.buf[nxt][0][ar * 32 + ak] = hh;
            *(s16x8*)&g.buf[nxt][1][ar * 32 + ak] = ll;
        }
        __syncthreads();
    }

#pragma unroll
    for (int f = 0; f < 4; ++f)
#pragma unroll
        for (int j = 0; j < 2; ++j) {
            const int n = nb * 128 + wn * 32 + j * 16 + rsel;
            const float bv = bih0[n];
#pragma unroll
            for (int jj = 0; jj < 4; ++jj) {
                const int m = wm * 64 + f * 16 + (lane >> 4) * 4 + jj;
                xg[((size_t)(b * 512 + q * 128 + m)) * 384 + n] = acc[f][j][jj] + bv;
            }
        }
    __syncthreads();   // drains stores (vmcnt0) + LDS reuse safety
}

// ---- xg1 task: xg1 chunk (b, c) = h1[b, 16c..16c+16) @ W_ih1^T + b_ih1 ----
__device__ void do_xg1_task(int j, int* __restrict__ xgflag,
        const float* __restrict__ h1, float* __restrict__ xg,
        const u16* __restrict__ w1h, const u16* __restrict__ w1l,
        const float* __restrict__ bih1, SmemX& smx)
{
    const int c = j >> 6, b = j & 63;
    const int tid = threadIdx.x, lane = tid & 63, wv = tid >> 6;
    const int rsel = lane & 15, koff = (lane >> 4) * 8;

    if (tid < 256) {   // stage h1 rows -> split bf16 hi/lo in LDS
        const int r = tid >> 4, c0 = (tid & 15) * 8;
        const float* p = h1 + ((size_t)(b * 512 + c * 16 + r)) * 128 + c0;
        f32x4 v0 = *(const f32x4*)p, v1 = *(const f32x4*)(p + 4);
        float fv[8] = {v0[0],v0[1],v0[2],v0[3], v1[0],v1[1],v1[2],v1[3]};
        s16x8 hh, ll; split8(fv, hh, ll);
        const int sc = c0 ^ ((r & 7) << 3);   // XOR-swizzle (T2)
        *(s16x8*)&smx.ah[r * 128 + sc] = hh;
        *(s16x8*)&smx.al[r * 128 + sc] = ll;
    }
    __syncthreads();

    f32x4 acc[3];
    const f32x4 vz = {0.f, 0.f, 0.f, 0.f};
    acc[0] = vz; acc[1] = vz; acc[2] = vz;
#pragma unroll
    for (int ks = 0; ks < 4; ++ks) {
        const int si = rsel * 128 + ((ks * 32 + koff) ^ ((rsel & 7) << 3));
        s16x8 a_h = *(const s16x8*)&smx.ah[si];
        s16x8 a_l = *(const s16x8*)&smx.al[si];
#pragma unroll
        for (int nf = 0; nf < 3; ++nf) {
            const int n = (3 * wv + nf) * 16 + rsel;
            s16x8 bh = *(const s16x8*)&w1h[(size_t)n * 128 + ks * 32 + koff];
            s16x8 bl = *(const s16x8*)&w1l[(size_t)n * 128 + ks * 32 + koff];
            acc[nf] = __builtin_amdgcn_mfma_f32_16x16x32_bf16(a_h, bh, acc[nf], 0, 0, 0);
            acc[nf] = __builtin_amdgcn_mfma_f32_16x16x32_bf16(a_h, bl, acc[nf], 0, 0, 0);
            acc[nf] = __builtin_amdgcn_mfma_f32_16x16x32_bf16(a_l, bh, acc[nf], 0, 0, 0);
        }
    }
#pragma unroll
    for (int nf = 0; nf < 3; ++nf) {
        const int n = (3 * wv + nf) * 16 + rsel;
        const float bv = bih1[n];
#pragma unroll
        for (int jj = 0; jj < 4; ++jj) {
            const int m = (lane >> 4) * 4 + jj;
            xg[((size_t)(b * 512 + c * 16 + m)) * 384 + n] = acc[nf][jj] + bv;
        }
    }
    __syncthreads();   // drains stores (vmcnt0)
    if (tid == 0) { __threadfence(); atomicExch(&xgflag[b * 32 + c], 1); }
}

// non-blocking drain of ready xg1 tasks (up to cap)
__device__ int drain_ready(int nextq, int cap, int* __restrict__ h1flag,
        int* __restrict__ xgflag, const float* __restrict__ h1,
        float* __restrict__ xg, const u16* __restrict__ w1h,
        const u16* __restrict__ w1l, const float* __restrict__ bih1, SmemX& smx)
{
    const int tid = threadIdx.x;
    for (int it = 0; it < cap && nextq < 2048; ++it) {
        if (tid == 0) {
            const int c = nextq >> 6, b = nextq & 63;
            int v = atomicAdd(&h1flag[b * 32 + c], 0);
            if (v) __threadfence();
            smx.decision = v;
        }
        __syncthreads();
        const int go = smx.decision;
        __syncthreads();
        if (!go) break;
        do_xg1_task(nextq, xgflag, h1, xg, w1h, w1l, bih1, smx);
        nextq += 128;
    }
    return nextq;
}

// ---- recurrence (r5 structure; L0 gated on gemmflag per t-quarter) ----

#define R_ISSUE(BUF, G) do {                                                  \
    const int _G = (G);                                                       \
    if (_G < 128 && tid < 128) {                                              \
        if (isL0) {                                                           \
            if ((_G & 31) == 0) {                                             \
                if ((tid & 63) == 0) {                                        \
                    while (atomicAdd(&gemmflag[b * 4 + (_G >> 5)], 0) == 0)   \
                        __builtin_amdgcn_s_sleep(16);                         \
                }                                                             \
                __threadfence();                                              \
            }                                                                 \
        } else {                                                              \
            if ((_G & 3) == 0) {                                              \
                if ((tid & 63) == 0) {                                        \
                    while (atomicAdd(&waitflag[b * 32 + (_G >> 2)], 0) == 0)  \
                        __builtin_amdgcn_s_sleep(8);                          \
                }                                                             \
                __threadfence();                                              \
            }                                                                 \
        }                                                                     \
        const float* _p = xgb + (size_t)(4 * _G) * 384 + tid;                 \
        BUF[0] = _p[0];    BUF[1] = _p[128];   BUF[2]  = _p[256];             \
        BUF[3] = _p[384];  BUF[4] = _p[512];   BUF[5]  = _p[640];             \
        BUF[6] = _p[768];  BUF[7] = _p[896];   BUF[8]  = _p[1024];            \
        BUF[9] = _p[1152]; BUF[10] = _p[1280]; BUF[11] = _p[1408];            \
    } } while (0)

#define R_STEP(T, BUF, J) do {                                                \
    const int _t = (T);                                                       \
    f32x4 _h0 = *(const f32x4*)(sm.hsh + 16 * w + 0);                         \
    f32x4 _h1 = *(const f32x4*)(sm.hsh + 16 * w + 4);                         \
    f32x4 _h2 = *(const f32x4*)(sm.hsh + 16 * w + 8);                         \
    f32x4 _h3 = *(const f32x4*)(sm.hsh + 16 * w + 12);                        \
    float _ha[16];                                                            \
    _ha[0]=_h0[0];  _ha[1]=_h0[1];  _ha[2]=_h0[2];  _ha[3]=_h0[3];            \
    _ha[4]=_h1[0];  _ha[5]=_h1[1];  _ha[6]=_h1[2];  _ha[7]=_h1[3];            \
    _ha[8]=_h2[0];  _ha[9]=_h2[1];  _ha[10]=_h2[2]; _ha[11]=_h2[3];           \
    _ha[12]=_h3[0]; _ha[13]=_h3[1]; _ha[14]=_h3[2]; _ha[15]=_h3[3];           \
    float _s0=0.f,_s1=0.f,_s2=0.f,_s3=0.f,_s4=0.f,_s5=0.f;                    \
    _Pragma("unroll")                                                         \
    for (int _i = 0; _i < 16; ++_i) {                                         \
        const float _hv = _ha[_i];                                            \
        _s0 = fmaf(_hv, wr[0][_i], _s0); _s1 = fmaf(_hv, wr[1][_i], _s1);     \
        _s2 = fmaf(_hv, wr[2][_i], _s2); _s3 = fmaf(_hv, wr[3][_i], _s3);     \
        _s4 = fmaf(_hv, wr[4][_i], _s4); _s5 = fmaf(_hv, wr[5][_i], _s5);     \
    }                                                                         \
    *(f32x2*)&sm.hp[w][g6 + 0] = (f32x2){_s0, _s1};                           \
    *(f32x2*)&sm.hp[w][g6 + 2] = (f32x2){_s2, _s3};                           \
    *(f32x2*)&sm.hp[w][g6 + 4] = (f32x2){_s4, _s5};                           \
    const bool _pub = isL0 && _t > 0 && (_t & 15) == 0;                       \
    if (_pub && tid < 128) asm volatile("s_waitcnt vmcnt(12)" ::: "memory");  \
    bar_lds();                                                                \
    if (_pub && tid == 0) {                                                   \
        __threadfence();                                                      \
        atomicExch(&setflag[b * 32 + ((_t >> 4) - 1)], 1);                    \
    }                                                                         \
    if (tid < 128) {                                                          \
        const int _c = tid;                                                   \
        float _hr = bhr, _hz = bhz, _hn = bhn;                                \
        _Pragma("unroll")                                                     \
        for (int _q = 0; _q < 8; ++_q) {                                      \
            _hr += sm.hp[_q][_c];                                             \
            _hz += sm.hp[_q][128 + _c];                                       \
            _hn += sm.hp[_q][256 + _c];                                       \
        }                                                                     \
        const float _xr = BUF[(J) * 3 + 0];                                   \
        const float _xz = BUF[(J) * 3 + 1];                                   \
        const float _xn = BUF[(J) * 3 + 2];                                   \
        const float _r = 1.f / (1.f + __expf(-(_xr + _hr)));                  \
        const float _z = 1.f / (1.f + __expf(-(_xz + _hz)));                  \
        float _a = _xn + _r * _hn;                                            \
        _a = fminf(fmaxf(_a, -15.f), 15.f);                                   \
        const float _e = __expf(2.f * _a);                                    \
        const float _n = (_e - 1.f) / (_e + 1.f);                             \
        hreg = (1.f - _z) * _n + _z * hreg;                                   \
        sm.hsh[_c] = hreg;                                                    \
        if (isL0) hseq[((size_t)(b * 512 + _t)) * 128 + _c] = hreg;           \
    }                                                                         \
    bar_lds();                                                                \
} while (0)

__device__ void recur_role(
    bool isL0, int b, const float* __restrict__ xg,
    const float* __restrict__ whh, const float* __restrict__ bhh,
    float* __restrict__ hseq, int* __restrict__ setflag, int* __restrict__ waitflag,
    int* __restrict__ gemmflag,
    const float* __restrict__ wfc1, const float* __restrict__ bfc1,
    const float* __restrict__ wfc2, const float* __restrict__ bfc2,
    float* __restrict__ out, SmemRecur& sm)
{
    const int tid  = threadIdx.x;       // 0..511
    const int w    = tid >> 6;          // k-slice 0..7 (wave-uniform)
    const int lane = tid & 63;
    const int g6   = 6 * lane;          // first of this lane's 6 gates
    (void)lane;

    // per-lane weights: wr[j][i] = whh[(g6+j)*128 + 16w + i]
    float wr[6][16];
#pragma unroll
    for (int j = 0; j < 6; ++j) {
        const float* p = whh + (size_t)(g6 + j) * 128 + 16 * w;
#pragma unroll
        for (int i4 = 0; i4 < 4; ++i4) {
            f32x4 v = *(const f32x4*)(p + 4 * i4);
            wr[j][4*i4+0] = v[0]; wr[j][4*i4+1] = v[1];
            wr[j][4*i4+2] = v[2]; wr[j][4*i4+3] = v[3];
        }
    }
    float bhr = 0.f, bhz = 0.f, bhn = 0.f, hreg = 0.f;
    if (tid < 128) {
        bhr = bhh[tid]; bhz = bhh[128 + tid]; bhn = bhh[256 + tid];
        sm.hsh[tid] = 0.f;
    }
    const float* xgb = xg + (size_t)b * 512 * 384;

    float pA[12], pB[12];
    R_ISSUE(pA, 0);
    R_ISSUE(pB, 1);
    __syncthreads();   // hsh init visible

    for (int gp = 0; gp < 64; ++gp) {
        const int t0 = gp * 8;
        R_STEP(t0 + 0, pA, 0); R_STEP(t0 + 1, pA, 1);
        R_STEP(t0 + 2, pA, 2); R_STEP(t0 + 3, pA, 3);
        R_ISSUE(pA, 2 * gp + 2);
        R_STEP(t0 + 4, pB, 0); R_STEP(t0 + 5, pB, 1);
        R_STEP(t0 + 6, pB, 2); R_STEP(t0 + 7, pB, 3);
        R_ISSUE(pB, 2 * gp + 3);
    }

    if (isL0) {   // final chunk publish
        if (tid < 128) asm volatile("s_waitcnt vmcnt(0)" ::: "memory");
        __syncthreads();
        if (tid == 0) { __threadfence(); atomicExch(&setflag[b * 32 + 31], 1); }
    }

    if (!isL0 && tid < 64) {   // fused MLP head
        const float* wv = wfc1 + tid * 128;
        float acc = bfc1[tid];
#pragma unroll 8
        for (int c = 0; c < 128; ++c) acc = fmaf(sm.hsh[c], wv[c], acc);
        float p = fmaxf(acc, 0.f) * wfc2[tid];
#pragma unroll
        for (int off = 32; off > 0; off >>= 1) p += __shfl_down(p, off);
        if (tid == 0) out[b] = p + bfc2[0];
    }
}

__device__ void worker_role(int wk,
        const float* __restrict__ x, const u16* __restrict__ w0h,
        const u16* __restrict__ w0l, const float* __restrict__ bih0,
        const float* __restrict__ h1, float* __restrict__ xg,
        const u16* __restrict__ w1h, const u16* __restrict__ w1l,
        const float* __restrict__ bih1, int* __restrict__ gemmflag,
        int* __restrict__ h1flag, int* __restrict__ xgflag, SmemWorker& sw)
{
    const int tid = threadIdx.x;
    int nextq = wk;   // xg1 tasks j = wk + 128n

    // ---- G0 phase: 2 panel-triples, quarter-major priority ----
#pragma unroll 1
    for (int rd = 0; rd < 2; ++rd) {
        const int p = wk + 128 * rd;           // 0..255
        const int q = p >> 6, b = p & 63;
#pragma unroll 1
        for (int nb = 0; nb < 3; ++nb) {
            g0_tile(b, q, nb, x, w0h, w0l, bih0, xg, sw.g0);
            nextq = drain_ready(nextq, 2, h1flag, xgflag, h1, xg,
                                w1h, w1l, bih1, sw.x);
        }
        // publish panel flag (tiles' stores drained by their __syncthreads)
        if (tid == 0) { __threadfence(); atomicExch(&gemmflag[b * 4 + q], 1); }
    }

    // ---- blocking finish of remaining xg1 tasks ----
    while (nextq < 2048) {
        if (tid == 0) {
            const int c = nextq >> 6, b = nextq & 63;
            while (atomicAdd(&h1flag[b * 32 + c], 0) == 0)
                __builtin_amdgcn_s_sleep(8);
            __threadfence();
        }
        __syncthreads();
        do_xg1_task(nextq, xgflag, h1, xg, w1h, w1l, bih1, sw.x);
        nextq += 128;
    }
}

__global__ __launch_bounds__(512, 2)
void k_fused(const float* __restrict__ x, float* __restrict__ xg,
             float* __restrict__ h1,
             const u16* __restrict__ w0h, const u16* __restrict__ w0l,
             const float* __restrict__ bih0,
             const float* __restrict__ whh0, const float* __restrict__ bhh0,
             const u16* __restrict__ w1h, const u16* __restrict__ w1l,
             const float* __restrict__ bih1,
             const float* __restrict__ whh1, const float* __restrict__ bhh1,
             const float* __restrict__ wfc1, const float* __restrict__ bfc1,
             const float* __restrict__ wfc2, const float* __restrict__ bfc2,
             float* __restrict__ out, int* __restrict__ gemmflag,
             int* __restrict__ h1flag, int* __restrict__ xgflag)
{
    __shared__ __align__(16) Smem sm;
    const int bid = blockIdx.x;
    if (bid < 64) {
        recur_role(true, bid, xg, whh0, bhh0, h1, h1flag, nullptr, gemmflag,
                   nullptr, nullptr, nullptr, nullptr, nullptr, sm.r);
    } else if (bid < 128) {
        recur_role(false, bid - 64, xg, whh1, bhh1, nullptr, nullptr, xgflag,
                   gemmflag, wfc1, bfc1, wfc2, bfc2, out, sm.r);
    } else {
        worker_role(bid - 128, x, w0h, w0l, bih0, h1, xg, w1h, w1l, bih1,
                    gemmflag, h1flag, xgflag, sm.w);
    }
}

extern "C" void kernel_launch(void* const* d_in, const int* in_sizes, int n_in,
                              void* d_out, int out_size, void* d_ws, size_t ws_size,
                              hipStream_t stream) {
    const float* x     = (const float*)d_in[0];
    const float* w_ih0 = (const float*)d_in[1];
    const float* w_hh0 = (const float*)d_in[2];
    const float* b_ih0 = (const float*)d_in[3];
    const float* b_hh0 = (const float*)d_in[4];
    const float* w_ih1 = (const float*)d_in[5];
    const float* w_hh1 = (const float*)d_in[6];
    const float* b_ih1 = (const float*)d_in[7];
    const float* b_hh1 = (const float*)d_in[8];
    const float* w_fc1 = (const float*)d_in[9];
    const float* b_fc1 = (const float*)d_in[10];
    const float* w_fc2 = (const float*)d_in[11];
    const float* b_fc2 = (const float*)d_in[12];
    float* out = (float*)d_out;
    (void)in_sizes; (void)n_in; (void)out_size; (void)ws_size;

    char* ws = (char*)d_ws;
    float* xg      = (float*)(ws + 0);          // 32768*384*4 (xg0, then xg1 in place)
    float* h1      = (float*)(ws + 50331648);   // 32768*128*4
    u16*   w0h     = (u16*)(ws + 67108864);     // 786432*2
    u16*   w0l     = (u16*)(ws + 68681728);     // 786432*2
    u16*   w1h     = (u16*)(ws + 70254592);     // 49152*2
    u16*   w1l     = (u16*)(ws + 70352896);     // 49152*2
    int*   h1flag  = (int*)(ws + 70451200);     // 2048 ints
    int*   xgflag  = h1flag + 2048;             // 2048 ints
    int*   gemmflag = xgflag + 2048;            // 256 ints

    k_zero<<<17, 256, 0, stream>>>(h1flag, 4352);
    k_split<<<3072, 256, 0, stream>>>(w_ih0, w0h, w0l, 384 * 2048);
    k_split<<<192, 256, 0, stream>>>(w_ih1, w1h, w1l, 384 * 128);
    k_fused<<<256, 512, 0, stream>>>(x, xg, h1, w0h, w0l, b_ih0, w_hh0, b_hh0,
                                     w1h, w1l, b_ih1, w_hh1, b_hh1,
                                     w_fc1, b_fc1, w_fc2, b_fc2,
                                     out, gemmflag, h1flag, xgflag);
}

// Round 13
// 629.112 us; speedup vs baseline: 1.4932x; 1.4932x over previous
//
#include <hip/hip_runtime.h>
#include <cstdint>
#include <cstddef>

typedef float f32x4 __attribute__((ext_vector_type(4)));
typedef float f32x2 __attribute__((ext_vector_type(2)));
typedef short s16x8 __attribute__((ext_vector_type(8)));
typedef unsigned short u16;

static __device__ __forceinline__ u16 f2bf(float f) {
    uint32_t x = __float_as_uint(f);
    x += 0x7fffu + ((x >> 16) & 1u);   // round-to-nearest-even to bf16
    return (u16)(x >> 16);
}
static __device__ __forceinline__ float bf2f(u16 h) {
    return __uint_as_float(((uint32_t)h) << 16);
}
static __device__ __forceinline__ void split8(const float* fv, s16x8& hh, s16x8& ll) {
#pragma unroll
    for (int i = 0; i < 8; ++i) {
        u16 h = f2bf(fv[i]); hh[i] = (short)h; ll[i] = (short)f2bf(fv[i] - bf2f(h));
    }
}

// Raw barrier with ONLY an LDS drain (no vmcnt) — global prefetch loads
// stay in flight across barriers.
static __device__ __forceinline__ void bar_lds() {
    asm volatile("s_waitcnt lgkmcnt(0)" ::: "memory");
    __builtin_amdgcn_s_barrier();
    asm volatile("" ::: "memory");
}

// ---------------- zero the pipeline flags (every launch; replay-safe) ------
__global__ void k_zero(int* __restrict__ p, int n) {
    int i = blockIdx.x * 256 + threadIdx.x;
    if (i < n) p[i] = 0;
}

// ---------------- split fp32 -> bf16 hi/lo ----------------
__global__ void k_split(const float* __restrict__ src, u16* __restrict__ hi,
                        u16* __restrict__ lo, int n) {
    int i = blockIdx.x * 256 + threadIdx.x;
    if (i < n) {
        float f = src[i];
        u16 h = f2bf(f);
        hi[i] = h;
        lo[i] = f2bf(f - bf2f(h));
    }
}

// ---------------- split-bf16 GEMM (layer-0 input projection) ----------------
// xg[32768,384] = x[32768,2048] @ W^T + b.  256 blocks (1/CU), 512 threads.
// BM=128, BN=384 (full N: A converted ONCE, no 3x redundancy), BK=32.
// Rows padded to 36 u16 (stride 72B -> bank-stride 18: conflict-free frag
// reads).  A+B single-buffered in LDS (72KB), reg-staged, 2 bar_lds()/kstep;
// global loads prefetched 2 ksteps ahead (held in regs across one kstep).
__global__ __launch_bounds__(512, 1)
void k_gemm(const float* __restrict__ A, const u16* __restrict__ Wh,
            const u16* __restrict__ Wl, const float* __restrict__ bias,
            float* __restrict__ C) {
    __shared__ __align__(16) u16 sAh[128 * 36];   // 9 KB
    __shared__ __align__(16) u16 sAl[128 * 36];
    __shared__ __align__(16) u16 sBh[384 * 36];   // 27 KB
    __shared__ __align__(16) u16 sBl[384 * 36];   // total 72 KB

    const int tid  = threadIdx.x;
    const int lane = tid & 63;
    const int wave = tid >> 6;
    const int wm = wave >> 2, wn = wave & 3;      // 2M x 4N wave grid
    const int rsel = lane & 15, koff = (lane >> 4) * 8;

    const long m0 = (long)blockIdx.x * 128;

    // staging coords
    const int ra = tid >> 2, ca = (tid & 3) * 8;          // A: row 0..127, col-chunk
    const float* aptr = A + (m0 + ra) * 2048 + ca;
    const int rb = tid >> 2, cb = (tid & 3) * 8;          // B: +c*128 rows

    f32x4 acc[4][6];
    const f32x4 vz = {0.f, 0.f, 0.f, 0.f};
#pragma unroll
    for (int f = 0; f < 4; ++f)
#pragma unroll
        for (int j = 0; j < 6; ++j) acc[f][j] = vz;

    f32x4 ar0, ar1;            // A prefetch regs (8 floats)
    s16x8 brh[3], brl[3];      // B prefetch regs (6 b128)

#define LOADK(K_) do {                                                        \
        const int _k = (K_);                                                  \
        ar0 = *(const f32x4*)(aptr + _k);                                     \
        ar1 = *(const f32x4*)(aptr + _k + 4);                                 \
        _Pragma("unroll")                                                     \
        for (int c = 0; c < 3; ++c) {                                         \
            const size_t off = (size_t)(c * 128 + rb) * 2048 + _k + cb;       \
            brh[c] = *(const s16x8*)(Wh + off);                               \
            brl[c] = *(const s16x8*)(Wl + off);                               \
        }                                                                     \
    } while (0)

#define STAGE() do {                                                          \
        float fv[8] = {ar0[0],ar0[1],ar0[2],ar0[3], ar1[0],ar1[1],ar1[2],ar1[3]}; \
        s16x8 hh, ll; split8(fv, hh, ll);                                     \
        *(s16x8*)&sAh[ra * 36 + ca] = hh;                                     \
        *(s16x8*)&sAl[ra * 36 + ca] = ll;                                     \
        _Pragma("unroll")                                                     \
        for (int c = 0; c < 3; ++c) {                                         \
            *(s16x8*)&sBh[(c * 128 + rb) * 36 + cb] = brh[c];                 \
            *(s16x8*)&sBl[(c * 128 + rb) * 36 + cb] = brl[c];                 \
        }                                                                     \
    } while (0)

    // prologue: k=0 staged, k=1 held in regs
    LOADK(0);
    STAGE();
    LOADK(32);
    __syncthreads();

    for (int ks = 0; ks < 64; ++ks) {
        // ---- compute on staged kstep ----
        {
            s16x8 ah[4], al[4];
#pragma unroll
            for (int f = 0; f < 4; ++f) {
                const int row = wm * 64 + f * 16 + rsel;
                ah[f] = *(const s16x8*)&sAh[row * 36 + koff];
                al[f] = *(const s16x8*)&sAl[row * 36 + koff];
            }
#pragma unroll
            for (int j = 0; j < 6; ++j) {
                const int n = wn * 96 + j * 16 + rsel;
                s16x8 bh = *(const s16x8*)&sBh[n * 36 + koff];
                s16x8 bl = *(const s16x8*)&sBl[n * 36 + koff];
#pragma unroll
                for (int f = 0; f < 4; ++f) {
                    acc[f][j] = __builtin_amdgcn_mfma_f32_16x16x32_bf16(ah[f], bh, acc[f][j], 0, 0, 0);
                    acc[f][j] = __builtin_amdgcn_mfma_f32_16x16x32_bf16(ah[f], bl, acc[f][j], 0, 0, 0);
                    acc[f][j] = __builtin_amdgcn_mfma_f32_16x16x32_bf16(al[f], bh, acc[f][j], 0, 0, 0);
                }
            }
        }
        bar_lds();                 // all LDS reads of this kstep complete
        if (ks < 63) {
            STAGE();               // write k=ks+1 (regs loaded last iter)
            if (ks < 62) LOADK((ks + 2) * 32);   // prefetch 2 ahead
        }
        bar_lds();                 // staged data visible for next compute
    }
#undef LOADK
#undef STAGE

    // ---- epilogue: bias + store ----
#pragma unroll
    for (int f = 0; f < 4; ++f) {
        const long mrow = m0 + wm * 64 + f * 16 + (lane >> 4) * 4;
#pragma unroll
        for (int j = 0; j < 6; ++j) {
            const int n = wn * 96 + j * 16 + rsel;
            const float bv = bias[n];
            float* o = C + mrow * 384 + n;
#pragma unroll
            for (int jj = 0; jj < 4; ++jj) o[(long)jj * 384] = acc[f][j][jj] + bv;
        }
    }
}

// =================== fused pipeline kernel (r5 champion, verbatim) ==========
// grid = 256 blocks x 512 threads, 1 block/CU (LDS-forced).
//   blocks   0..63 : layer-0 recurrence (produce h1 + flag per 16-step chunk)
//   blocks  64..127: layer-1 recurrence (consume xgflag) + MLP head
//   blocks 128..255: GEMM workers: xg1 = h1 @ w_ih1^T + b_ih1 (W_ih1 in regs)

struct SmemRecur { float hsh[128]; float hp[8][384]; };
struct SmemGemm  { u16 ah[16 * 128]; u16 al[16 * 128]; };
union Smem {
    SmemRecur r;
    SmemGemm  g;
    char force_one_block_per_cu[98304];   // 96KB: strictly 1 block/CU
};

#define R_ISSUE(BUF, G) do {                                                  \
    const int _G = (G);                                                       \
    if (_G < 128 && tid < 128) {                                              \
        if (!isL0 && (_G & 3) == 0) {                                         \
            if ((tid & 63) == 0) {                                            \
                while (atomicAdd(&waitflag[b * 32 + (_G >> 2)], 0) == 0)      \
                    __builtin_amdgcn_s_sleep(8);                              \
            }                                                                 \
            __threadfence();                                                  \
        }                                                                     \
        const float* _p = xgb + (size_t)(4 * _G) * 384 + tid;                 \
        BUF[0] = _p[0];    BUF[1] = _p[128];   BUF[2]  = _p[256];             \
        BUF[3] = _p[384];  BUF[4] = _p[512];   BUF[5]  = _p[640];             \
        BUF[6] = _p[768];  BUF[7] = _p[896];   BUF[8]  = _p[1024];            \
        BUF[9] = _p[1152]; BUF[10] = _p[1280]; BUF[11] = _p[1408];            \
    } } while (0)

#define R_STEP(T, BUF, J) do {                                                \
    const int _t = (T);                                                       \
    f32x4 _h0 = *(const f32x4*)(sm.hsh + 16 * w + 0);                         \
    f32x4 _h1 = *(const f32x4*)(sm.hsh + 16 * w + 4);                         \
    f32x4 _h2 = *(const f32x4*)(sm.hsh + 16 * w + 8);                         \
    f32x4 _h3 = *(const f32x4*)(sm.hsh + 16 * w + 12);                        \
    float _ha[16];                                                            \
    _ha[0]=_h0[0];  _ha[1]=_h0[1];  _ha[2]=_h0[2];  _ha[3]=_h0[3];            \
    _ha[4]=_h1[0];  _ha[5]=_h1[1];  _ha[6]=_h1[2];  _ha[7]=_h1[3];            \
    _ha[8]=_h2[0];  _ha[9]=_h2[1];  _ha[10]=_h2[2]; _ha[11]=_h2[3];           \
    _ha[12]=_h3[0]; _ha[13]=_h3[1]; _ha[14]=_h3[2]; _ha[15]=_h3[3];           \
    float _s0=0.f,_s1=0.f,_s2=0.f,_s3=0.f,_s4=0.f,_s5=0.f;                    \
    _Pragma("unroll")                                                         \
    for (int _i = 0; _i < 16; ++_i) {                                         \
        const float _hv = _ha[_i];                                            \
        _s0 = fmaf(_hv, wr[0][_i], _s0); _s1 = fmaf(_hv, wr[1][_i], _s1);     \
        _s2 = fmaf(_hv, wr[2][_i], _s2); _s3 = fmaf(_hv, wr[3][_i], _s3);     \
        _s4 = fmaf(_hv, wr[4][_i], _s4); _s5 = fmaf(_hv, wr[5][_i], _s5);     \
    }                                                                         \
    *(f32x2*)&sm.hp[w][g6 + 0] = (f32x2){_s0, _s1};                           \
    *(f32x2*)&sm.hp[w][g6 + 2] = (f32x2){_s2, _s3};                           \
    *(f32x2*)&sm.hp[w][g6 + 4] = (f32x2){_s4, _s5};                           \
    const bool _pub = isL0 && _t > 0 && (_t & 15) == 0;                       \
    if (_pub && tid < 128) asm volatile("s_waitcnt vmcnt(12)" ::: "memory");  \
    bar_lds();                                                                \
    if (_pub && tid == 0) {                                                   \
        __threadfence();                                                      \
        atomicExch(&setflag[b * 32 + ((_t >> 4) - 1)], 1);                    \
    }                                                                         \
    if (tid < 128) {                                                          \
        const int _c = tid;                                                   \
        float _hr = bhr, _hz = bhz, _hn = bhn;                                \
        _Pragma("unroll")                                                     \
        for (int _q = 0; _q < 8; ++_q) {                                      \
            _hr += sm.hp[_q][_c];                                             \
            _hz += sm.hp[_q][128 + _c];                                       \
            _hn += sm.hp[_q][256 + _c];                                       \
        }                                                                     \
        const float _xr = BUF[(J) * 3 + 0];                                   \
        const float _xz = BUF[(J) * 3 + 1];                                   \
        const float _xn = BUF[(J) * 3 + 2];                                   \
        const float _r = 1.f / (1.f + __expf(-(_xr + _hr)));                  \
        const float _z = 1.f / (1.f + __expf(-(_xz + _hz)));                  \
        float _a = _xn + _r * _hn;                                            \
        _a = fminf(fmaxf(_a, -15.f), 15.f);                                   \
        const float _e = __expf(2.f * _a);                                    \
        const float _n = (_e - 1.f) / (_e + 1.f);                             \
        hreg = (1.f - _z) * _n + _z * hreg;                                   \
        sm.hsh[_c] = hreg;                                                    \
        if (isL0) hseq[((size_t)(b * 512 + _t)) * 128 + _c] = hreg;           \
    }                                                                         \
    bar_lds();                                                                \
} while (0)

__device__ void recur_role(
    bool isL0, int b, const float* __restrict__ xg,
    const float* __restrict__ whh, const float* __restrict__ bhh,
    float* __restrict__ hseq, int* __restrict__ setflag, int* __restrict__ waitflag,
    const float* __restrict__ wfc1, const float* __restrict__ bfc1,
    const float* __restrict__ wfc2, const float* __restrict__ bfc2,
    float* __restrict__ out, SmemRecur& sm)
{
    const int tid  = threadIdx.x;       // 0..511
    const int w    = tid >> 6;          // k-slice 0..7 (wave-uniform)
    const int lane = tid & 63;
    const int g6   = 6 * lane;          // first of this lane's 6 gates
    (void)lane;

    // per-lane weights: wr[j][i] = whh[(g6+j)*128 + 16w + i]
    float wr[6][16];
#pragma unroll
    for (int j = 0; j < 6; ++j) {
        const float* p = whh + (size_t)(g6 + j) * 128 + 16 * w;
#pragma unroll
        for (int i4 = 0; i4 < 4; ++i4) {
            f32x4 v = *(const f32x4*)(p + 4 * i4);
            wr[j][4*i4+0] = v[0]; wr[j][4*i4+1] = v[1];
            wr[j][4*i4+2] = v[2]; wr[j][4*i4+3] = v[3];
        }
    }
    float bhr = 0.f, bhz = 0.f, bhn = 0.f, hreg = 0.f;
    if (tid < 128) {
        bhr = bhh[tid]; bhz = bhh[128 + tid]; bhn = bhh[256 + tid];
        sm.hsh[tid] = 0.f;
    }
    const float* xgb = xg + (size_t)b * 512 * 384;

    float pA[12], pB[12];
    R_ISSUE(pA, 0);
    R_ISSUE(pB, 1);
    __syncthreads();   // hsh init visible

    for (int gp = 0; gp < 64; ++gp) {
        const int t0 = gp * 8;
        R_STEP(t0 + 0, pA, 0); R_STEP(t0 + 1, pA, 1);
        R_STEP(t0 + 2, pA, 2); R_STEP(t0 + 3, pA, 3);
        R_ISSUE(pA, 2 * gp + 2);
        R_STEP(t0 + 4, pB, 0); R_STEP(t0 + 5, pB, 1);
        R_STEP(t0 + 6, pB, 2); R_STEP(t0 + 7, pB, 3);
        R_ISSUE(pB, 2 * gp + 3);
    }

    if (isL0) {   // final chunk publish
        if (tid < 128) asm volatile("s_waitcnt vmcnt(0)" ::: "memory");
        __syncthreads();
        if (tid == 0) { __threadfence(); atomicExch(&setflag[b * 32 + 31], 1); }
    }

    if (!isL0 && tid < 64) {   // fused MLP head
        const float* wv = wfc1 + tid * 128;
        float acc = bfc1[tid];
#pragma unroll 8
        for (int c = 0; c < 128; ++c) acc = fmaf(sm.hsh[c], wv[c], acc);
        float p = fmaxf(acc, 0.f) * wfc2[tid];
#pragma unroll
        for (int off = 32; off > 0; off >>= 1) p += __shfl_down(p, off);
        if (tid == 0) out[b] = p + bfc2[0];
    }
}

__device__ void worker_role(
    int wk, const float* __restrict__ h1, float* __restrict__ xg,
    const float* __restrict__ wih1, const float* __restrict__ bih1,
    int* __restrict__ h1flag, int* __restrict__ xgflag, SmemGemm& sm)
{
    const int tid = threadIdx.x, lane = tid & 63, w = tid >> 6;   // 8 waves
    const int rsel = lane & 15, koff = (lane >> 4) * 8;

    // persistent W_ih1 fragments: wave w owns n-frags {3w, 3w+1, 3w+2}
    s16x8 bh[3][4], bl[3][4];
    float bias[3];
#pragma unroll
    for (int nfi = 0; nfi < 3; ++nfi) {
        const int n = (3 * w + nfi) * 16 + rsel;
        bias[nfi] = bih1[n];
#pragma unroll
        for (int ks = 0; ks < 4; ++ks) {
            const float* p = wih1 + n * 128 + ks * 32 + koff;
            f32x4 v0 = *(const f32x4*)p, v1 = *(const f32x4*)(p + 4);
            float fv[8] = {v0[0],v0[1],v0[2],v0[3], v1[0],v1[1],v1[2],v1[3]};
            s16x8 hh, ll;
            split8(fv, hh, ll);
            bh[nfi][ks] = hh; bl[nfi][ks] = ll;
        }
    }

    for (int jt = wk; jt < 2048; jt += 128) {
        const int c = jt >> 6, b = jt & 63;     // chunk 0..31, batch 0..63
        if (tid == 0) {
            while (atomicAdd(&h1flag[b * 32 + c], 0) == 0) __builtin_amdgcn_s_sleep(8);
            __threadfence();
        }
        __syncthreads();
        // stage A = h1 rows (b, 16c..16c+15): fp32 -> split bf16 hi/lo in LDS
        if (tid < 256) {
            const int r = tid >> 4, c0 = (tid & 15) * 8;
            const float* p = h1 + ((size_t)(b * 512 + c * 16 + r)) * 128 + c0;
            f32x4 v0 = *(const f32x4*)p, v1 = *(const f32x4*)(p + 4);
            float fv[8] = {v0[0],v0[1],v0[2],v0[3], v1[0],v1[1],v1[2],v1[3]};
            s16x8 hh, ll;
            split8(fv, hh, ll);
            const int sc = c0 ^ ((r & 7) << 3);   // XOR-swizzle (T2)
            *(s16x8*)&sm.ah[r * 128 + sc] = hh;
            *(s16x8*)&sm.al[r * 128 + sc] = ll;
        }
        __syncthreads();

        f32x4 acc[3];
        const f32x4 vz = {0.f, 0.f, 0.f, 0.f};
        acc[0] = vz; acc[1] = vz; acc[2] = vz;
#pragma unroll
        for (int ks = 0; ks < 4; ++ks) {
            const int si = rsel * 128 + ((ks * 32 + koff) ^ ((rsel & 7) << 3));
            s16x8 a_h = *(const s16x8*)&sm.ah[si];
            s16x8 a_l = *(const s16x8*)&sm.al[si];
#pragma unroll
            for (int nfi = 0; nfi < 3; ++nfi) {
                acc[nfi] = __builtin_amdgcn_mfma_f32_16x16x32_bf16(a_h, bh[nfi][ks], acc[nfi], 0, 0, 0);
                acc[nfi] = __builtin_amdgcn_mfma_f32_16x16x32_bf16(a_h, bl[nfi][ks], acc[nfi], 0, 0, 0);
                acc[nfi] = __builtin_amdgcn_mfma_f32_16x16x32_bf16(a_l, bh[nfi][ks], acc[nfi], 0, 0, 0);
            }
        }
        // epilogue: xg1 rows overwrite consumed xg0 rows (safe: flag order)
#pragma unroll
        for (int nfi = 0; nfi < 3; ++nfi) {
            const int n = (3 * w + nfi) * 16 + rsel;
#pragma unroll
            for (int jj = 0; jj < 4; ++jj) {
                const int m = (lane >> 4) * 4 + jj;
                xg[((size_t)(b * 512 + c * 16 + m)) * 384 + n] = acc[nfi][jj] + bias[nfi];
            }
        }
        __syncthreads();   // drains stores (vmcnt0) + LDS reuse safety
        if (tid == 0) {
            __threadfence();
            atomicExch(&xgflag[b * 32 + c], 1);
        }
    }
}

__global__ __launch_bounds__(512, 2)
void k_fused(float* __restrict__ xg, float* __restrict__ h1,
             const float* __restrict__ whh0, const float* __restrict__ bhh0,
             const float* __restrict__ wih1, const float* __restrict__ bih1,
             const float* __restrict__ whh1, const float* __restrict__ bhh1,
             const float* __restrict__ wfc1, const float* __restrict__ bfc1,
             const float* __restrict__ wfc2, const float* __restrict__ bfc2,
             float* __restrict__ out, int* __restrict__ h1flag, int* __restrict__ xgflag)
{
    __shared__ __align__(16) Smem sm;
    const int bid = blockIdx.x;
    if (bid < 64) {
        recur_role(true, bid, xg, whh0, bhh0, h1, h1flag, nullptr,
                   nullptr, nullptr, nullptr, nullptr, nullptr, sm.r);
    } else if (bid < 128) {
        recur_role(false, bid - 64, xg, whh1, bhh1, nullptr, nullptr, xgflag,
                   wfc1, bfc1, wfc2, bfc2, out, sm.r);
    } else {
        worker_role(bid - 128, h1, xg, wih1, bih1, h1flag, xgflag, sm.g);
    }
}

extern "C" void kernel_launch(void* const* d_in, const int* in_sizes, int n_in,
                              void* d_out, int out_size, void* d_ws, size_t ws_size,
                              hipStream_t stream) {
    const float* x     = (const float*)d_in[0];
    const float* w_ih0 = (const float*)d_in[1];
    const float* w_hh0 = (const float*)d_in[2];
    const float* b_ih0 = (const float*)d_in[3];
    const float* b_hh0 = (const float*)d_in[4];
    const float* w_ih1 = (const float*)d_in[5];
    const float* w_hh1 = (const float*)d_in[6];
    const float* b_ih1 = (const float*)d_in[7];
    const float* b_hh1 = (const float*)d_in[8];
    const float* w_fc1 = (const float*)d_in[9];
    const float* b_fc1 = (const float*)d_in[10];
    const float* w_fc2 = (const float*)d_in[11];
    const float* b_fc2 = (const float*)d_in[12];
    float* out = (float*)d_out;
    (void)in_sizes; (void)n_in; (void)out_size; (void)ws_size;

    char* ws = (char*)d_ws;
    float* xg     = (float*)(ws + 0);          // 32768*384*4 (xg0, then xg1 in place)
    float* h1     = (float*)(ws + 50331648);   // 32768*128*4
    u16*   w0h    = (u16*)(ws + 67108864);     // 786432*2
    u16*   w0l    = (u16*)(ws + 68681728);     // 786432*2
    int*   h1flag = (int*)(ws + 70254592);     // 2048 ints
    int*   xgflag = h1flag + 2048;             // 2048 ints

    k_zero<<<16, 256, 0, stream>>>(h1flag, 4096);
    k_split<<<3072, 256, 0, stream>>>(w_ih0, w0h, w0l, 384 * 2048);
    k_gemm<<<256, 512, 0, stream>>>(x, w0h, w0l, b_ih0, xg);
    k_fused<<<256, 512, 0, stream>>>(xg, h1, w_hh0, b_hh0, w_ih1, b_ih1,
                                     w_hh1, b_hh1, w_fc1, b_fc1, w_fc2, b_fc2,
                                     out, h1flag, xgflag);
}